// Round 24
// baseline (96.243 us; speedup 1.0000x reference)
//
#include <hip/hip_runtime.h>
#include <math.h>

#define BB 32
#define LL 256
#define DD 16
#define HH 64
#define KK 5
#define TT 252          // LL - KK + 1
#define PP 126          // TT/2
#define SS 8064         // HH*PP
#define NCHUNK 14
#define CHUNK 576       // 14*576 = 8064
#define NSTEP 36        // K=16 steps per chunk
#define NG 6            // groups of 6 steps (96 k's) per chunk
#define NSB 8           // s-slices for scores
#define SLICE 1008      // SS / NSB

typedef __attribute__((ext_vector_type(8))) short bf16x8;
typedef __attribute__((ext_vector_type(16))) float f32x16;

__device__ __forceinline__ unsigned short f2bf(float f) {
  unsigned int u = __float_as_uint(f);
  u += 0x7FFFu + ((u >> 16) & 1u);          // round-to-nearest-even
  return (unsigned short)(u >> 16);
}
__device__ __forceinline__ float bf2f(unsigned short h) {
  return __uint_as_float(((unsigned int)h) << 16);
}

// ---------------- kernel 12: conv + relu + recon + pool (fused per (b,d)) --
__global__ __launch_bounds__(256) void k12_conv_recon(
    const float* __restrict__ x, const float* __restrict__ cw,
    const float* __restrict__ cb, const float* __restrict__ dw,
    const float* __restrict__ db, float* __restrict__ flat,
    unsigned short* __restrict__ mainH, unsigned short* __restrict__ mainL,
    float* __restrict__ recon) {
  __shared__ float ylds[HH * TT];   // 64*252 = 16128 f = 64512 B
  __shared__ float xs[LL];
  __shared__ float cws[HH * KK];
  __shared__ float dws[HH * KK];
  __shared__ float cbs[HH];

  int bd = blockIdx.x;              // b*DD + d
  int b = bd / DD, d = bd % DD;
  int tid = threadIdx.x;

  // x stage: aligned float4 within the row, select d&3
  {
    float4 xv = *(const float4*)(x + ((size_t)b * LL + tid) * DD + (d & ~3));
    int dl = d & 3;
    float v = (dl == 0) ? xv.x : (dl == 1) ? xv.y : (dl == 2) ? xv.z : xv.w;
    xs[tid] = v;
  }
  for (int i = tid; i < HH * KK; i += 256) {
    cws[i] = cw[(size_t)d * HH * KK + i];
    dws[i] = dw[(size_t)d * HH * KK + i];
  }
  if (tid < HH) cbs[tid] = cb[d * HH + tid];
  __syncthreads();

  {
    int h = tid >> 2, a = tid & 3;
    int t0 = a * 63;
    float w0 = cws[h * KK + 0], w1 = cws[h * KK + 1], w2 = cws[h * KK + 2],
          w3 = cws[h * KK + 3], w4 = cws[h * KK + 4];
    float bias = cbs[h];
    float x0 = xs[t0], x1 = xs[t0 + 1], x2 = xs[t0 + 2], x3 = xs[t0 + 3],
          x4 = xs[t0 + 4];
    float* yrow = ylds + h * TT + t0;
    #pragma unroll 7
    for (int t = 0; t < 63; ++t) {
      float yv = fmaf(w4, x4, fmaf(w3, x3, fmaf(w2, x2, fmaf(w1, x1, fmaf(w0, x0, bias)))));
      yrow[t] = fmaxf(yv, 0.f);
      x0 = x1; x1 = x2; x2 = x3; x3 = x4;
      if (t < 62) x4 = xs[t0 + t + 5];
    }
  }
  __syncthreads();

  for (int i = tid; i < HH * PP; i += 256) {
    int h = i / PP, p = i - h * PP;
    float pooled = 0.5f * (ylds[h * TT + 2 * p] + ylds[h * TT + 2 * p + 1]);
    flat[(size_t)bd * SS + i] = pooled;
    if (d == 0) {
      unsigned short hb = f2bf(pooled);
      mainH[(size_t)b * SS + i] = hb;
      mainL[(size_t)b * SS + i] = f2bf(pooled - bf2f(hb));
    }
  }

  {
    int l = tid;
    float acc = db[d];
    for (int h = 0; h < HH; ++h) {
      const float* yl = ylds + h * TT;
      #pragma unroll
      for (int j = 0; j < KK; ++j) {
        int t = l - j;
        if (t >= 0 && t < TT) acc = fmaf(yl[t], dws[h * KK + j], acc);
      }
    }
    recon[(size_t)bd * LL + l] = acc;
  }
}

// ---------------- kernel 3: partial = main @ W_attn -------------------------
// v19: W NEVER touches LDS. mfma_f32_32x32x16_bf16; each wave owns a 32-col
// tile (block = 128 cols, every W element read once). Per K=16 step: 8
// coalesced W dwords direct to regs (B frag = W[k0+koct*8+e][n0+colq],
// verified r16/r17), in-reg f2bf, 2 MFMA (Ah*Wh + Al*Wh; single-bf16 W
// verified r18-r22). A (hi+lo) staged in LDS per 96-k group: 24 KB dbuf,
// ONE barrier per 6 steps; W prefetch (3 rotating sets, depth 2) crosses
// barriers freely since barriers only fence A. Layouts: A row=lane&31,
// k=(lane>>5)*8+e; D col=lane&31, row=(r&3)+8*(r>>2)+4*(lane>>5) [m74/m101].
#define BARRIER_NODRAIN() do {                                        \
    asm volatile("s_waitcnt lgkmcnt(0)" ::: "memory");                \
    __builtin_amdgcn_s_barrier();                                     \
  } while (0)

__global__ __launch_bounds__(256) void k3_mfma(
    const float* __restrict__ W, const unsigned short* __restrict__ mainH,
    const unsigned short* __restrict__ mainL, float* __restrict__ partial) {
  __shared__ unsigned short AH[2][3072];   // [buf][oct*256 + row*8], oct<12
  __shared__ unsigned short AL[2][3072];   // total 24 KB

  int tid = threadIdx.x;
  int lane = tid & 63;
  int wv = tid >> 6;            // 0..3, wave owns 32-col tile
  int chunk = blockIdx.y;
  int s0 = chunk * CHUNK;
  int n0 = blockIdx.x * 128 + wv * 32;
  int colq = lane & 31;
  int koct = lane >> 5;         // 0,1

  const float* wb = W + (size_t)(s0 + koct * 8) * SS + n0 + colq;

  f32x16 acc;
  #pragma unroll
  for (int r = 0; r < 16; ++r) acc[r] = 0.f;

  // W pipeline: 3 rotating named sets of 8 floats
  float wA0, wA1, wA2, wA3, wA4, wA5, wA6, wA7;
  float wB0, wB1, wB2, wB3, wB4, wB5, wB6, wB7;
  float wC0, wC1, wC2, wC3, wC4, wC5, wC6, wC7;
  // A staging regs (group g+1 / g+2 in flight)
  bf16x8 aH1, aL1, aH2, aL2;

  int arow = tid & 31, aoct = tid >> 5;    // staging decomposition

#define LOADW(P, T) if ((T) < NSTEP) {                                \
    const float* p_ = wb + (size_t)(T) * 16 * SS;                     \
    P##0 = p_[0];                P##1 = p_[(size_t)SS];               \
    P##2 = p_[2 * (size_t)SS];   P##3 = p_[3 * (size_t)SS];           \
    P##4 = p_[4 * (size_t)SS];   P##5 = p_[5 * (size_t)SS];           \
    P##6 = p_[6 * (size_t)SS];   P##7 = p_[7 * (size_t)SS]; }

#define LOADA(G) {                                                    \
    size_t kb_ = (size_t)s0 + (size_t)(G) * 96;                       \
    aH1 = *(const bf16x8*)(mainH + (size_t)arow * SS + kb_ + aoct * 8); \
    aL1 = *(const bf16x8*)(mainL + (size_t)arow * SS + kb_ + aoct * 8); \
    if (tid < 128) {                                                  \
      aH2 = *(const bf16x8*)(mainH + (size_t)arow * SS + kb_ + (aoct + 8) * 8); \
      aL2 = *(const bf16x8*)(mainL + (size_t)arow * SS + kb_ + (aoct + 8) * 8); \
    } }

#define WRITEA(BUF) {                                                 \
    *(bf16x8*)&AH[BUF][tid * 8] = aH1;                                \
    *(bf16x8*)&AL[BUF][tid * 8] = aL1;                                \
    if (tid < 128) {                                                  \
      *(bf16x8*)&AH[BUF][(tid + 256) * 8] = aH2;                      \
      *(bf16x8*)&AL[BUF][(tid + 256) * 8] = aL2;                      \
    } }

#define CONSUME(P, KS, BUF) {                                         \
    bf16x8 bh;                                                        \
    bh[0] = (short)f2bf(P##0); bh[1] = (short)f2bf(P##1);             \
    bh[2] = (short)f2bf(P##2); bh[3] = (short)f2bf(P##3);             \
    bh[4] = (short)f2bf(P##4); bh[5] = (short)f2bf(P##5);             \
    bh[6] = (short)f2bf(P##6); bh[7] = (short)f2bf(P##7);             \
    int aoff_ = ((KS) * 2 + koct) * 256 + colq * 8;                   \
    bf16x8 ah = *(const bf16x8*)&AH[BUF][aoff_];                      \
    bf16x8 al = *(const bf16x8*)&AL[BUF][aoff_];                      \
    acc = __builtin_amdgcn_mfma_f32_32x32x16_bf16(ah, bh, acc, 0, 0, 0); \
    acc = __builtin_amdgcn_mfma_f32_32x32x16_bf16(al, bh, acc, 0, 0, 0); }

  // prologue: A(0) -> buf0; A(1) -> regs; W steps 0,1 -> sets A,B
  LOADA(0)
  WRITEA(0)
  LOADA(1)
  LOADW(wA, 0)
  LOADW(wB, 1)
  __syncthreads();

  #pragma unroll 1
  for (int g = 0; g < NG; ++g) {
    int base = g * 6;
    int buf = g & 1;
    LOADW(wC, base + 2)  CONSUME(wA, 0, buf)
    LOADW(wA, base + 3)  CONSUME(wB, 1, buf)
    LOADW(wB, base + 4)  CONSUME(wC, 2, buf)
    LOADW(wC, base + 5)  CONSUME(wA, 3, buf)
    LOADW(wA, base + 6)  CONSUME(wB, 4, buf)
    LOADW(wB, base + 7)  CONSUME(wC, 5, buf)
    if (g + 1 < NG) { WRITEA(buf ^ 1) }
    if (g + 2 < NG) { LOADA(g + 2) }
    if (g + 1 < NG) BARRIER_NODRAIN();
  }

  // epilogue: D col=lane&31, row=(r&3)+8*(r>>2)+4*koct  (r16/r17-verified)
  float* pp = partial + (size_t)chunk * BB * SS + n0 + colq;
  #pragma unroll
  for (int r = 0; r < 16; ++r) {
    int row = (r & 3) + 8 * (r >> 2) + 4 * koct;
    pp[(size_t)row * SS] = acc[r];
  }
#undef LOADW
#undef LOADA
#undef WRITEA
#undef CONSUME
}

// ---------------- kernel 4: fused partial-reduce + scores -------------------
__global__ __launch_bounds__(256) void k4_scores(
    const float* __restrict__ partial, const float* __restrict__ flat,
    float* __restrict__ pscores) {
  int sb = blockIdx.x;            // 0..7
  int b = blockIdx.y;             // 0..31
  int tid = threadIdx.x;

  float acc[15];
  #pragma unroll
  for (int dd = 0; dd < 15; ++dd) acc[dd] = 0.f;

  const float* pb = partial + (size_t)b * SS;
  const float* fb = flat + (size_t)b * DD * SS;

  for (int s = sb * SLICE + tid; s < (sb + 1) * SLICE; s += 256) {
    float mv = 0.f;
    #pragma unroll
    for (int c = 0; c < NCHUNK; ++c)
      mv += pb[(size_t)c * (BB * SS) + s];
    #pragma unroll
    for (int dd = 0; dd < 15; ++dd)
      acc[dd] = fmaf(mv, fb[(size_t)(1 + dd) * SS + s], acc[dd]);
  }

  #pragma unroll
  for (int dd = 0; dd < 15; ++dd) {
    float v = acc[dd];
    #pragma unroll
    for (int o = 32; o; o >>= 1) v += __shfl_xor(v, o);
    acc[dd] = v;
  }
  __shared__ float red[4][15];
  if ((tid & 63) == 0) {
    int w = tid >> 6;
    #pragma unroll
    for (int dd = 0; dd < 15; ++dd) red[w][dd] = acc[dd];
  }
  __syncthreads();
  if (tid < 15)
    pscores[(size_t)sb * (BB * 15) + b * 15 + tid] =
        red[0][tid] + red[1][tid] + red[2][tid] + red[3][tid];
}

// ---------------- kernel 6: softmax (from pscores) + main copy + weighted ---
__global__ __launch_bounds__(256) void k6_out(
    const float* __restrict__ flat, const float* __restrict__ pscores,
    float* __restrict__ out, float* __restrict__ attn_out) {
  int b = blockIdx.y;
  int s = blockIdx.x * 256 + threadIdx.x;

#define SUMS(DD_) ({ float t_ = 0.f;                                   \
    _Pragma("unroll")                                                  \
    for (int sb_ = 0; sb_ < NSB; ++sb_)                                \
      t_ += pscores[(size_t)sb_ * (BB * 15) + b * 15 + (DD_)];         \
    t_; })
  float v0 = SUMS(0),  v1 = SUMS(1),  v2 = SUMS(2),  v3 = SUMS(3),
        v4 = SUMS(4),  v5 = SUMS(5),  v6 = SUMS(6),  v7 = SUMS(7),
        v8 = SUMS(8),  v9 = SUMS(9),  v10 = SUMS(10), v11 = SUMS(11),
        v12 = SUMS(12), v13 = SUMS(13), v14 = SUMS(14);
#undef SUMS
  float mx = -INFINITY;
  mx = fmaxf(mx, v0);  mx = fmaxf(mx, v1);  mx = fmaxf(mx, v2);
  mx = fmaxf(mx, v3);  mx = fmaxf(mx, v4);  mx = fmaxf(mx, v5);
  mx = fmaxf(mx, v6);  mx = fmaxf(mx, v7);  mx = fmaxf(mx, v8);
  mx = fmaxf(mx, v9);  mx = fmaxf(mx, v10); mx = fmaxf(mx, v11);
  mx = fmaxf(mx, v12); mx = fmaxf(mx, v13); mx = fmaxf(mx, v14);
  float a0 = expf(v0 - mx), a1 = expf(v1 - mx), a2 = expf(v2 - mx),
        a3 = expf(v3 - mx), a4 = expf(v4 - mx), a5 = expf(v5 - mx),
        a6 = expf(v6 - mx), a7 = expf(v7 - mx), a8 = expf(v8 - mx),
        a9 = expf(v9 - mx), a10 = expf(v10 - mx), a11 = expf(v11 - mx),
        a12 = expf(v12 - mx), a13 = expf(v13 - mx), a14 = expf(v14 - mx);
  float sum = a0 + a1 + a2 + a3 + a4 + a5 + a6 + a7 + a8 + a9 + a10 + a11 +
              a12 + a13 + a14;
  float inv = 1.f / sum;

  if (blockIdx.x == 0 && threadIdx.x < 15) {
    float v = 0.f;
    #pragma unroll
    for (int sb_ = 0; sb_ < NSB; ++sb_)
      v += pscores[(size_t)sb_ * (BB * 15) + b * 15 + threadIdx.x];
    attn_out[b * 15 + threadIdx.x] = expf(v - mx) * inv;
  }

  if (s >= SS) return;
  const float* fb = flat + (size_t)b * DD * SS;
  out[(size_t)b * 2 * SS + s] = fb[s];
  float w = 0.f;
  w = fmaf(a0 * inv,  fb[(size_t)1 * SS + s], w);
  w = fmaf(a1 * inv,  fb[(size_t)2 * SS + s], w);
  w = fmaf(a2 * inv,  fb[(size_t)3 * SS + s], w);
  w = fmaf(a3 * inv,  fb[(size_t)4 * SS + s], w);
  w = fmaf(a4 * inv,  fb[(size_t)5 * SS + s], w);
  w = fmaf(a5 * inv,  fb[(size_t)6 * SS + s], w);
  w = fmaf(a6 * inv,  fb[(size_t)7 * SS + s], w);
  w = fmaf(a7 * inv,  fb[(size_t)8 * SS + s], w);
  w = fmaf(a8 * inv,  fb[(size_t)9 * SS + s], w);
  w = fmaf(a9 * inv,  fb[(size_t)10 * SS + s], w);
  w = fmaf(a10 * inv, fb[(size_t)11 * SS + s], w);
  w = fmaf(a11 * inv, fb[(size_t)12 * SS + s], w);
  w = fmaf(a12 * inv, fb[(size_t)13 * SS + s], w);
  w = fmaf(a13 * inv, fb[(size_t)14 * SS + s], w);
  w = fmaf(a14 * inv, fb[(size_t)15 * SS + s], w);
  out[(size_t)b * 2 * SS + SS + s] = w;
}

// ---------------------------------------------------------------------------
extern "C" void kernel_launch(void* const* d_in, const int* in_sizes, int n_in,
                              void* d_out, int out_size, void* d_ws, size_t ws_size,
                              hipStream_t stream) {
  const float* x        = (const float*)d_in[0];
  const float* conv_w   = (const float*)d_in[1];
  const float* conv_b   = (const float*)d_in[2];
  const float* deconv_w = (const float*)d_in[3];
  const float* deconv_b = (const float*)d_in[4];
  const float* W_attn   = (const float*)d_in[5];
  float* out = (float*)d_out;

  // output layout: [ out (516096) | attn (480) | recon (131072) ]
  const size_t ATTN_OFF  = (size_t)BB * 2 * SS;        // 516096
  const size_t RECON_OFF = ATTN_OFF + (size_t)BB * 15; // 516576

  // workspace layout; all 16B-aligned
  float* ws      = (float*)d_ws;
  float* partial = ws;                                        // 14*32*8064 f
  float* flat    = partial + (size_t)NCHUNK * BB * SS;        // 4,128,768 f
  unsigned short* mainH = (unsigned short*)(flat + (size_t)BB * DD * SS);
  unsigned short* mainL = mainH + (size_t)BB * SS;            // 258,048 u16
  float* pscores = (float*)(mainL + (size_t)BB * SS);         // 8*480 f

  // 1) fused conv+relu+recon+pool (+ bf16 hi/lo split of main)
  k12_conv_recon<<<dim3(BB * DD), dim3(256), 0, stream>>>(
      x, conv_w, conv_b, deconv_w, deconv_b, flat, mainH, mainL, out + RECON_OFF);

  // 2) big matmul partials: 32x32 MFMA, W direct-to-reg (no W LDS)
  k3_mfma<<<dim3(SS / 128, NCHUNK), dim3(256), 0, stream>>>(
      W_attn, mainH, mainL, partial);

  // 3) fused partial-reduce + scores
  k4_scores<<<dim3(NSB, BB), dim3(256), 0, stream>>>(partial, flat, pscores);

  // 4) fused softmax + main copy + weighted
  k6_out<<<dim3((SS + 255) / 256, BB), dim3(256), 0, stream>>>(
      flat, pscores, out, out + ATTN_OFF);
}

// Round 25
// 89.713 us; speedup vs baseline: 1.0728x; 1.0728x over previous
//
#include <hip/hip_runtime.h>
#include <math.h>

#define BB 32
#define LL 256
#define DD 16
#define HH 64
#define KK 5
#define TT 252          // LL - KK + 1
#define PP 126          // TT/2
#define SS 8064         // HH*PP
#define NCHUNK 12
#define CHUNK 672       // 12*672 = 8064
#define NKT 21          // K-tiles (32) per chunk
#define NSB 8           // s-slices for scores
#define SLICE 1008      // SS / NSB

typedef __attribute__((ext_vector_type(8))) short bf16x8;
typedef __attribute__((ext_vector_type(4))) float f32x4;

__device__ __forceinline__ unsigned short f2bf(float f) {
  unsigned int u = __float_as_uint(f);
  u += 0x7FFFu + ((u >> 16) & 1u);          // round-to-nearest-even
  return (unsigned short)(u >> 16);
}
__device__ __forceinline__ float bf2f(unsigned short h) {
  return __uint_as_float(((unsigned int)h) << 16);
}

// ---------------- kernel 12: conv + relu + recon + pool (fused per (b,d)) --
__global__ __launch_bounds__(256) void k12_conv_recon(
    const float* __restrict__ x, const float* __restrict__ cw,
    const float* __restrict__ cb, const float* __restrict__ dw,
    const float* __restrict__ db, float* __restrict__ flat,
    unsigned short* __restrict__ mainH, unsigned short* __restrict__ mainL,
    float* __restrict__ recon) {
  __shared__ float ylds[HH * TT];   // 64*252 = 16128 f = 64512 B
  __shared__ float xs[LL];
  __shared__ float cws[HH * KK];
  __shared__ float dws[HH * KK];
  __shared__ float cbs[HH];

  int bd = blockIdx.x;              // b*DD + d
  int b = bd / DD, d = bd % DD;
  int tid = threadIdx.x;

  // x stage: aligned float4 within the row, select d&3
  {
    float4 xv = *(const float4*)(x + ((size_t)b * LL + tid) * DD + (d & ~3));
    int dl = d & 3;
    float v = (dl == 0) ? xv.x : (dl == 1) ? xv.y : (dl == 2) ? xv.z : xv.w;
    xs[tid] = v;
  }
  for (int i = tid; i < HH * KK; i += 256) {
    cws[i] = cw[(size_t)d * HH * KK + i];
    dws[i] = dw[(size_t)d * HH * KK + i];
  }
  if (tid < HH) cbs[tid] = cb[d * HH + tid];
  __syncthreads();

  {
    int h = tid >> 2, a = tid & 3;
    int t0 = a * 63;
    float w0 = cws[h * KK + 0], w1 = cws[h * KK + 1], w2 = cws[h * KK + 2],
          w3 = cws[h * KK + 3], w4 = cws[h * KK + 4];
    float bias = cbs[h];
    float x0 = xs[t0], x1 = xs[t0 + 1], x2 = xs[t0 + 2], x3 = xs[t0 + 3],
          x4 = xs[t0 + 4];
    float* yrow = ylds + h * TT + t0;
    #pragma unroll 7
    for (int t = 0; t < 63; ++t) {
      float yv = fmaf(w4, x4, fmaf(w3, x3, fmaf(w2, x2, fmaf(w1, x1, fmaf(w0, x0, bias)))));
      yrow[t] = fmaxf(yv, 0.f);
      x0 = x1; x1 = x2; x2 = x3; x3 = x4;
      if (t < 62) x4 = xs[t0 + t + 5];
    }
  }
  __syncthreads();

  for (int i = tid; i < HH * PP; i += 256) {
    int h = i / PP, p = i - h * PP;
    float pooled = 0.5f * (ylds[h * TT + 2 * p] + ylds[h * TT + 2 * p + 1]);
    flat[(size_t)bd * SS + i] = pooled;
    if (d == 0) {
      unsigned short hb = f2bf(pooled);
      mainH[(size_t)b * SS + i] = hb;
      mainL[(size_t)b * SS + i] = f2bf(pooled - bf2f(hb));
    }
  }

  {
    int l = tid;
    float acc = db[d];
    for (int h = 0; h < HH; ++h) {
      const float* yl = ylds + h * TT;
      #pragma unroll
      for (int j = 0; j < KK; ++j) {
        int t = l - j;
        if (t >= 0 && t < TT) acc = fmaf(yl[t], dws[h * KK + j], acc);
      }
    }
    recon[(size_t)bd * LL + l] = acc;
  }
}

// ---------------- kernel 3: partial = main @ W_attn via bf16 MFMA -----------
// v16 (round-21 best): v11 pipeline — loads-at-top, even/odd reg sets,
// 1 barrier/K-tile, 128-col blocks, NCHUNK=12 — W single-bf16 (RNE), 24 KB
// LDS. Terms: m = Ah*Wh + Al*Wh.
__global__ __launch_bounds__(256) void k3_mfma(
    const float* __restrict__ W, const unsigned short* __restrict__ mainH,
    const unsigned short* __restrict__ mainL, float* __restrict__ partial) {
  __shared__ unsigned short AH[2][1024];   // [buf][aq*256 + ab*8]   2x2 KB
  __shared__ unsigned short AL[2][1024];
  __shared__ unsigned short BH[2][4096];   // [buf][sg*1024 + c*8]   2x8 KB

  int tid = threadIdx.x;
  int chunk = blockIdx.y;
  int s0 = chunk * CHUNK;
  int cbase = blockIdx.x * 128;

  int lane = tid & 63;
  int wv = tid >> 6;
  int mr = wv & 1;              // row-tile (batches 16mr..16mr+15)
  int ctb = (wv >> 1) * 4;      // 4 col-tiles per wave

  f32x4 c0 = {0.f, 0.f, 0.f, 0.f};
  f32x4 c1 = {0.f, 0.f, 0.f, 0.f};
  f32x4 c2 = {0.f, 0.f, 0.f, 0.f};
  f32x4 c3 = {0.f, 0.f, 0.f, 0.f};

  int sc2 = (tid & 63) * 2;     // staging col pair
  int sg = tid >> 6;            // staging k-octet
  const float* wbase = W + (size_t)(s0 + sg * 8) * SS + cbase + sc2;

  int ab = tid >> 2, aq = tid & 3;            // A staging (tid<128)
  size_t abase = (size_t)ab * SS + (size_t)(s0 + aq * 8);

  int aoff  = (lane >> 4) * 256 + ((lane & 15) + 16 * mr) * 8;
  int boff0 = (lane >> 4) * 1024 + (ctb * 16 + (lane & 15)) * 8;

  // pipeline registers: even/odd tile sets
  float2 e0, e1, e2, e3, e4, e5, e6, e7;
  float2 o0, o1, o2, o3, o4, o5, o6, o7;
  bf16x8 aEH, aEL, aOH, aOL;

#define LOADW(R0,R1,R2,R3,R4,R5,R6,R7, KT) {                          \
    const float* p_ = wbase + (size_t)(KT) * 32 * SS;                 \
    R0 = *(const float2*)(p_);                                        \
    R1 = *(const float2*)(p_ + (size_t)SS);                           \
    R2 = *(const float2*)(p_ + 2 * (size_t)SS);                       \
    R3 = *(const float2*)(p_ + 3 * (size_t)SS);                       \
    R4 = *(const float2*)(p_ + 4 * (size_t)SS);                       \
    R5 = *(const float2*)(p_ + 5 * (size_t)SS);                       \
    R6 = *(const float2*)(p_ + 6 * (size_t)SS);                       \
    R7 = *(const float2*)(p_ + 7 * (size_t)SS); }

#define LOADA(RH, RL, KT) if (tid < 128) {                            \
    RH = *(const bf16x8*)(mainH + abase + (KT) * 32);                 \
    RL = *(const bf16x8*)(mainL + abase + (KT) * 32); }

#define CVT1(F, J) {                                                  \
    h0[J] = (short)f2bf(F.x);                                         \
    h1[J] = (short)f2bf(F.y); }

#define CVTW(R0,R1,R2,R3,R4,R5,R6,R7, BUF) {                          \
    bf16x8 h0, h1;                                                    \
    CVT1(R0, 0) CVT1(R1, 1) CVT1(R2, 2) CVT1(R3, 3)                   \
    CVT1(R4, 4) CVT1(R5, 5) CVT1(R6, 6) CVT1(R7, 7)                   \
    *(bf16x8*)&BH[BUF][sg * 1024 + sc2 * 8]     = h0;                 \
    *(bf16x8*)&BH[BUF][sg * 1024 + sc2 * 8 + 8] = h1; }

#define WRITEA(RH, RL, BUF) if (tid < 128) {                          \
    *(bf16x8*)&AH[BUF][aq * 256 + ab * 8] = RH;                       \
    *(bf16x8*)&AL[BUF][aq * 256 + ab * 8] = RL; }

#define DOMFMA(BUF) {                                                 \
    bf16x8 ah  = *(const bf16x8*)&AH[BUF][aoff];                      \
    bf16x8 al  = *(const bf16x8*)&AL[BUF][aoff];                      \
    bf16x8 bh0 = *(const bf16x8*)&BH[BUF][boff0];                     \
    bf16x8 bh1 = *(const bf16x8*)&BH[BUF][boff0 + 128];               \
    bf16x8 bh2 = *(const bf16x8*)&BH[BUF][boff0 + 256];               \
    bf16x8 bh3 = *(const bf16x8*)&BH[BUF][boff0 + 384];               \
    c0 = __builtin_amdgcn_mfma_f32_16x16x32_bf16(ah, bh0, c0, 0, 0, 0); \
    c0 = __builtin_amdgcn_mfma_f32_16x16x32_bf16(al, bh0, c0, 0, 0, 0); \
    c1 = __builtin_amdgcn_mfma_f32_16x16x32_bf16(ah, bh1, c1, 0, 0, 0); \
    c1 = __builtin_amdgcn_mfma_f32_16x16x32_bf16(al, bh1, c1, 0, 0, 0); \
    c2 = __builtin_amdgcn_mfma_f32_16x16x32_bf16(ah, bh2, c2, 0, 0, 0); \
    c2 = __builtin_amdgcn_mfma_f32_16x16x32_bf16(al, bh2, c2, 0, 0, 0); \
    c3 = __builtin_amdgcn_mfma_f32_16x16x32_bf16(ah, bh3, c3, 0, 0, 0); \
    c3 = __builtin_amdgcn_mfma_f32_16x16x32_bf16(al, bh3, c3, 0, 0, 0); }

  // prologue: tile0 -> buf0 (via even regs); tile1 -> odd regs
  LOADW(e0,e1,e2,e3,e4,e5,e6,e7, 0) LOADA(aEH, aEL, 0)
  CVTW(e0,e1,e2,e3,e4,e5,e6,e7, 0) WRITEA(aEH, aEL, 0)
  LOADW(o0,o1,o2,o3,o4,o5,o6,o7, 1) LOADA(aOH, aOL, 1)
  __syncthreads();

  #pragma unroll 1
  for (int kt = 0; kt < NKT - 1; kt += 2) {
    // even tile kt: loads FIRST (max in-flight distance before barrier)
    LOADW(e0,e1,e2,e3,e4,e5,e6,e7, kt + 2) LOADA(aEH, aEL, kt + 2)
    DOMFMA(0)
    CVTW(o0,o1,o2,o3,o4,o5,o6,o7, 1) WRITEA(aOH, aOL, 1)
    __syncthreads();
    // odd tile kt+1
    if (kt + 3 < NKT) {
      LOADW(o0,o1,o2,o3,o4,o5,o6,o7, kt + 3) LOADA(aOH, aOL, kt + 3)
    }
    DOMFMA(1)
    CVTW(e0,e1,e2,e3,e4,e5,e6,e7, 0) WRITEA(aEH, aEL, 0)
    __syncthreads();
  }
  DOMFMA(0)   // tail tile NKT-1 = 20 (even buf)

  // epilogue: D col=lane&15, row=(lane>>4)*4+reg  (v11-verified)
  int row0 = mr * 16 + (lane >> 4) * 4;
  int col0 = cbase + ctb * 16 + (lane & 15);
  float* pp = partial + ((size_t)chunk * BB + row0) * SS + col0;
  #pragma unroll
  for (int r = 0; r < 4; ++r) pp[(size_t)r * SS]      = c0[r];
  #pragma unroll
  for (int r = 0; r < 4; ++r) pp[(size_t)r * SS + 16] = c1[r];
  #pragma unroll
  for (int r = 0; r < 4; ++r) pp[(size_t)r * SS + 32] = c2[r];
  #pragma unroll
  for (int r = 0; r < 4; ++r) pp[(size_t)r * SS + 48] = c3[r];
#undef LOADW
#undef LOADA
#undef CVT1
#undef CVTW
#undef WRITEA
#undef DOMFMA
}

// ---------------- kernel 4: fused partial-reduce + scores -------------------
__global__ __launch_bounds__(256) void k4_scores(
    const float* __restrict__ partial, const float* __restrict__ flat,
    float* __restrict__ pscores) {
  int sb = blockIdx.x;            // 0..7
  int b = blockIdx.y;             // 0..31
  int tid = threadIdx.x;

  float acc[15];
  #pragma unroll
  for (int dd = 0; dd < 15; ++dd) acc[dd] = 0.f;

  const float* pb = partial + (size_t)b * SS;
  const float* fb = flat + (size_t)b * DD * SS;

  for (int s = sb * SLICE + tid; s < (sb + 1) * SLICE; s += 256) {
    float mv = 0.f;
    #pragma unroll
    for (int c = 0; c < NCHUNK; ++c)
      mv += pb[(size_t)c * (BB * SS) + s];
    #pragma unroll
    for (int dd = 0; dd < 15; ++dd)
      acc[dd] = fmaf(mv, fb[(size_t)(1 + dd) * SS + s], acc[dd]);
  }

  #pragma unroll
  for (int dd = 0; dd < 15; ++dd) {
    float v = acc[dd];
    #pragma unroll
    for (int o = 32; o; o >>= 1) v += __shfl_xor(v, o);
    acc[dd] = v;
  }
  __shared__ float red[4][15];
  if ((tid & 63) == 0) {
    int w = tid >> 6;
    #pragma unroll
    for (int dd = 0; dd < 15; ++dd) red[w][dd] = acc[dd];
  }
  __syncthreads();
  if (tid < 15)
    pscores[(size_t)sb * (BB * 15) + b * 15 + tid] =
        red[0][tid] + red[1][tid] + red[2][tid] + red[3][tid];
}

// ---------------- kernel 6: softmax (from pscores) + main copy + weighted ---
__global__ __launch_bounds__(256) void k6_out(
    const float* __restrict__ flat, const float* __restrict__ pscores,
    float* __restrict__ out, float* __restrict__ attn_out) {
  int b = blockIdx.y;
  int s = blockIdx.x * 256 + threadIdx.x;

#define SUMS(DD_) ({ float t_ = 0.f;                                   \
    _Pragma("unroll")                                                  \
    for (int sb_ = 0; sb_ < NSB; ++sb_)                                \
      t_ += pscores[(size_t)sb_ * (BB * 15) + b * 15 + (DD_)];         \
    t_; })
  float v0 = SUMS(0),  v1 = SUMS(1),  v2 = SUMS(2),  v3 = SUMS(3),
        v4 = SUMS(4),  v5 = SUMS(5),  v6 = SUMS(6),  v7 = SUMS(7),
        v8 = SUMS(8),  v9 = SUMS(9),  v10 = SUMS(10), v11 = SUMS(11),
        v12 = SUMS(12), v13 = SUMS(13), v14 = SUMS(14);
#undef SUMS
  float mx = -INFINITY;
  mx = fmaxf(mx, v0);  mx = fmaxf(mx, v1);  mx = fmaxf(mx, v2);
  mx = fmaxf(mx, v3);  mx = fmaxf(mx, v4);  mx = fmaxf(mx, v5);
  mx = fmaxf(mx, v6);  mx = fmaxf(mx, v7);  mx = fmaxf(mx, v8);
  mx = fmaxf(mx, v9);  mx = fmaxf(mx, v10); mx = fmaxf(mx, v11);
  mx = fmaxf(mx, v12); mx = fmaxf(mx, v13); mx = fmaxf(mx, v14);
  float a0 = expf(v0 - mx), a1 = expf(v1 - mx), a2 = expf(v2 - mx),
        a3 = expf(v3 - mx), a4 = expf(v4 - mx), a5 = expf(v5 - mx),
        a6 = expf(v6 - mx), a7 = expf(v7 - mx), a8 = expf(v8 - mx),
        a9 = expf(v9 - mx), a10 = expf(v10 - mx), a11 = expf(v11 - mx),
        a12 = expf(v12 - mx), a13 = expf(v13 - mx), a14 = expf(v14 - mx);
  float sum = a0 + a1 + a2 + a3 + a4 + a5 + a6 + a7 + a8 + a9 + a10 + a11 +
              a12 + a13 + a14;
  float inv = 1.f / sum;

  if (blockIdx.x == 0 && threadIdx.x < 15) {
    float v = 0.f;
    #pragma unroll
    for (int sb_ = 0; sb_ < NSB; ++sb_)
      v += pscores[(size_t)sb_ * (BB * 15) + b * 15 + threadIdx.x];
    attn_out[b * 15 + threadIdx.x] = expf(v - mx) * inv;
  }

  if (s >= SS) return;
  const float* fb = flat + (size_t)b * DD * SS;
  out[(size_t)b * 2 * SS + s] = fb[s];
  float w = 0.f;
  w = fmaf(a0 * inv,  fb[(size_t)1 * SS + s], w);
  w = fmaf(a1 * inv,  fb[(size_t)2 * SS + s], w);
  w = fmaf(a2 * inv,  fb[(size_t)3 * SS + s], w);
  w = fmaf(a3 * inv,  fb[(size_t)4 * SS + s], w);
  w = fmaf(a4 * inv,  fb[(size_t)5 * SS + s], w);
  w = fmaf(a5 * inv,  fb[(size_t)6 * SS + s], w);
  w = fmaf(a6 * inv,  fb[(size_t)7 * SS + s], w);
  w = fmaf(a7 * inv,  fb[(size_t)8 * SS + s], w);
  w = fmaf(a8 * inv,  fb[(size_t)9 * SS + s], w);
  w = fmaf(a9 * inv,  fb[(size_t)10 * SS + s], w);
  w = fmaf(a10 * inv, fb[(size_t)11 * SS + s], w);
  w = fmaf(a11 * inv, fb[(size_t)12 * SS + s], w);
  w = fmaf(a12 * inv, fb[(size_t)13 * SS + s], w);
  w = fmaf(a13 * inv, fb[(size_t)14 * SS + s], w);
  w = fmaf(a14 * inv, fb[(size_t)15 * SS + s], w);
  out[(size_t)b * 2 * SS + SS + s] = w;
}

// ---------------------------------------------------------------------------
extern "C" void kernel_launch(void* const* d_in, const int* in_sizes, int n_in,
                              void* d_out, int out_size, void* d_ws, size_t ws_size,
                              hipStream_t stream) {
  const float* x        = (const float*)d_in[0];
  const float* conv_w   = (const float*)d_in[1];
  const float* conv_b   = (const float*)d_in[2];
  const float* deconv_w = (const float*)d_in[3];
  const float* deconv_b = (const float*)d_in[4];
  const float* W_attn   = (const float*)d_in[5];
  float* out = (float*)d_out;

  // output layout: [ out (516096) | attn (480) | recon (131072) ]
  const size_t ATTN_OFF  = (size_t)BB * 2 * SS;        // 516096
  const size_t RECON_OFF = ATTN_OFF + (size_t)BB * 15; // 516576

  // workspace layout; all 16B-aligned
  float* ws      = (float*)d_ws;
  float* partial = ws;                                        // 12*32*8064 f
  float* flat    = partial + (size_t)NCHUNK * BB * SS;        // 4,128,768 f
  unsigned short* mainH = (unsigned short*)(flat + (size_t)BB * DD * SS);
  unsigned short* mainL = mainH + (size_t)BB * SS;            // 258,048 u16
  float* pscores = (float*)(mainL + (size_t)BB * SS);         // 8*480 f

  // 1) fused conv+relu+recon+pool (+ bf16 hi/lo split of main)
  k12_conv_recon<<<dim3(BB * DD), dim3(256), 0, stream>>>(
      x, conv_w, conv_b, deconv_w, deconv_b, flat, mainH, mainL, out + RECON_OFF);

  // 2) big matmul partials via MFMA (v16: v11 pipeline, single-bf16 W, 24 KB LDS)
  k3_mfma<<<dim3(SS / 128, NCHUNK), dim3(256), 0, stream>>>(
      W_attn, mainH, mainL, partial);

  // 3) fused partial-reduce + scores
  k4_scores<<<dim3(NSB, BB), dim3(256), 0, stream>>>(partial, flat, pscores);

  // 4) fused softmax + main copy + weighted
  k6_out<<<dim3((SS + 255) / 256, BB), dim3(256), 0, stream>>>(
      flat, pscores, out, out + ATTN_OFF);
}